// Round 15
// baseline (164.090 us; speedup 1.0000x reference)
//
#include <hip/hip_runtime.h>
#include <hip/hip_fp16.h>
#include <math.h>

// SSIM loss: ZERO-BARRIER wave-decoupled MFMA pipeline.
// Each wave owns a private LDS pane (48 rows x 32 cols x 2 planes, f16,
// 80B row stride) holding exactly its K=32 banded H-window (cols cw-8..cw+23,
// rows R0-5..R0+36; rows 42-47 zero-init, never written -> zero-pad band).
// Per tile: write prefetched regs -> pane; 6 ds_read_b128 fragments (rows
// 16mt+cl, k-bytes 16am); issue next tile's global loads; 12 banded K=32
// H-MFMAs (Bh[j]=g[8am+j-cl-3]); f16-convert D once per (q,mt); V-blur
// register-chained via 16x16x16 MFMA (Av1[j]=g[4am+j-cl],
// Av2[j]=g[4am+j+16-cl]); SSIM on 8 reg pixels. All DS ops are wave-private
// and the LDS pipeline is in-order per wave -> no __syncthreads in the loop.
// All numerics validated r11-r14 (absmax 0.0).

#define HH 512
#define WW 512
#define HW (HH*WW)
#define NPLANES 48
#define G_TILES 6
#define NBLOCKS 1024           // 6144 tiles / 6

typedef _Float16 f16x8 __attribute__((ext_vector_type(8)));
typedef _Float16 f16x4 __attribute__((ext_vector_type(4)));
typedef float f32x4 __attribute__((ext_vector_type(4)));

#define ROW_B   80             // bytes per pane row (64 used); %128=80 -> <=2-way
#define PLANE_B 3840           // 48*80
#define WAVE_B  7680           // 2 planes
#define LDS_TOTAL 30720        // 4 waves

struct WParam { float A, B; };

__global__ void ssim_init_out(float* out) { out[0] = 1.0f; }

__global__ __launch_bounds__(256, 4)
void ssim_mfma(const float* __restrict__ img, const float* __restrict__ tgt,
               float* __restrict__ out, WParam wp) {
    __shared__ alignas(16) char lds[LDS_TOTAL];
    __shared__ float wsum[4];

    const int tid  = threadIdx.x;
    const int wid  = tid >> 6;
    const int lane = tid & 63;
    const int cl   = lane & 15;
    const int am   = lane >> 4;
    char* wb = lds + wid * WAVE_B;

    // ---- once: zero pane rows 42-47, both planes (never written again) ----
    #pragma unroll
    for (int i = 0; i < 2; ++i) {
        int s = lane + 64 * i;
        if (s < 120) {                       // 2 planes * 6 rows * 10 slots(8B)
            int q = s / 60, o = s - 60 * q;
            *(float2*)(wb + q * PLANE_B + 42 * ROW_B + o * 8)
                = make_float2(0.f, 0.f);
        }
    }

    // ---- per-lane weight fragments (validated r11/r13) ----
    f16x8 Bh;
    #pragma unroll
    for (int j = 0; j < 8; ++j) {
        int ih = 8*am + j - cl - 3;
        float t = (float)(ih - 5);
        Bh[j] = ((unsigned)ih <= 10u) ? (_Float16)(wp.A * exp2f(-wp.B*t*t))
                                      : (_Float16)0.f;
    }
    f16x4 Av1, Av2;
    #pragma unroll
    for (int j = 0; j < 4; ++j) {
        int k = 4*am + j;
        int i1 = k - cl;
        float t1 = (float)(i1 - 5);
        Av1[j] = ((unsigned)i1 <= 10u) ? (_Float16)(wp.A * exp2f(-wp.B*t1*t1))
                                       : (_Float16)0.f;
        int i2 = k + 16 - cl;
        float t2 = (float)(i2 - 5);
        Av2[j] = ((unsigned)i2 <= 10u) ? (_Float16)(wp.A * exp2f(-wp.B*t2*t2))
                                       : (_Float16)0.f;
    }

    const int slot = lane & 7;           // float4 slot within 32-col window
    const int sub  = lane >> 3;          // row-within-8 group
    float4 pre[12];                      // prefetch: x rows(6), y rows(6)

    auto issue_loads = [&](int tlin) {
        const int p   = tlin >> 7;
        const int rem = tlin & 127;
        const int R0  = (rem >> 3) * 32;
        const int C0  = (rem & 7) * 64;
        const int cw  = C0 + 16 * wid;
        const int gc  = cw - 8 + 4 * slot;
        const bool cv = (unsigned)gc <= 508u;
        const float* ip = img + (size_t)p * HW;
        const float* tp = tgt + (size_t)p * HW;
        const float4 z = make_float4(0.f, 0.f, 0.f, 0.f);
        #pragma unroll
        for (int t = 0; t < 6; ++t) {
            int gr = R0 - 5 + 8*t + sub;
            bool v = cv && ((unsigned)gr < (unsigned)HH);
            size_t off = (size_t)gr * WW + gc;
            pre[t]     = v ? *(const float4*)(ip + off) : z;
            pre[6 + t] = v ? *(const float4*)(tp + off) : z;
        }
    };

    auto write_stage = [&]() {
        #pragma unroll
        for (int t = 0; t < 6; ++t) {
            int row = 8*t + sub;
            if (t < 5 || sub < 2) {          // rows 42-47 stay zero
                float4 X = pre[t], Y = pre[6 + t];
                f16x4 hx, hy;
                hx[0]=(_Float16)X.x; hx[1]=(_Float16)X.y;
                hx[2]=(_Float16)X.z; hx[3]=(_Float16)X.w;
                hy[0]=(_Float16)Y.x; hy[1]=(_Float16)Y.y;
                hy[2]=(_Float16)Y.z; hy[3]=(_Float16)Y.w;
                char* dst = wb + row * ROW_B + slot * 8;
                *(f16x4*)(dst)           = hx;
                *(f16x4*)(dst + PLANE_B) = hy;
            }
        }
    };

    const int base_t = blockIdx.x * G_TILES;
    issue_loads(base_t);

    const float C1 = 1e-4f, C2 = 9e-4f;
    float lsum = 0.f;

    for (int g = 0; g < G_TILES; ++g) {
        // stage this tile (waits vmcnt for pre); wave-private, no barrier
        write_stage();

        // fragment reads (in-order DS after the writes above)
        f16x8 hx3[3], hy3[3];
        #pragma unroll
        for (int mt = 0; mt < 3; ++mt) {
            const char* src = wb + (16*mt + cl) * ROW_B + am * 16;
            hx3[mt] = *(const f16x8*)(src);
            hy3[mt] = *(const f16x8*)(src + PLANE_B);
        }

        // overlap next tile's HBM latency under compute
        if (g + 1 < G_TILES) issue_loads(base_t + g + 1);

        // H-blur: 12 banded K=32 MFMAs; convert D to f16 once per (q,mt)
        f16x4 D16[4][3];
        #pragma unroll
        for (int q = 0; q < 4; ++q) {
            #pragma unroll
            for (int mt = 0; mt < 3; ++mt) {
                f16x8 A = (q == 0) ? hx3[mt]
                        : (q == 1) ? hy3[mt]
                        : (q == 2) ? (f16x8)(hx3[mt]*hx3[mt] + hy3[mt]*hy3[mt])
                                   : (f16x8)(hx3[mt]*hy3[mt]);
                f32x4 zz = {0.f, 0.f, 0.f, 0.f};
                f32x4 d = __builtin_amdgcn_mfma_f32_16x16x32_f16(A, Bh, zz, 0, 0, 0);
                f16x4 h;
                h[0]=(_Float16)d[0]; h[1]=(_Float16)d[1];
                h[2]=(_Float16)d[2]; h[3]=(_Float16)d[3];
                D16[q][mt] = h;
            }
        }

        // V-blur (register-chained 16x16x16) + SSIM
        #pragma unroll
        for (int mtv = 0; mtv < 2; ++mtv) {
            f32x4 accv[4];
            #pragma unroll
            for (int q = 0; q < 4; ++q) {
                f32x4 zz = {0.f, 0.f, 0.f, 0.f};
                f32x4 a = __builtin_amdgcn_mfma_f32_16x16x16f16(Av2, D16[q][mtv+1], zz, 0, 0, 0);
                accv[q] = __builtin_amdgcn_mfma_f32_16x16x16f16(Av1, D16[q][mtv],   a,  0, 0, 0);
            }
            #pragma unroll
            for (int j = 0; j < 4; ++j) {
                float mu1 = accv[0][j], mu2 = accv[1][j];
                float bss = accv[2][j], bxy = accv[3][j];
                float mu1s = mu1*mu1, mu2s = mu2*mu2, mu12 = mu1*mu2;
                float ssum = bss - mu1s - mu2s;
                float s12  = bxy - mu12;
                float num = (2.f*mu12 + C1) * (2.f*s12 + C2);
                float den = (mu1s + mu2s + C1) * (ssum + C2);
                lsum = fmaf(num, __builtin_amdgcn_rcpf(den), lsum);
            }
        }
    }

    // ---- block reduction + one atomic ----
    for (int off = 32; off > 0; off >>= 1)
        lsum += __shfl_down(lsum, off, 64);
    if (lane == 0) wsum[wid] = lsum;
    __syncthreads();
    if (tid == 0) {
        float bsum = wsum[0] + wsum[1] + wsum[2] + wsum[3];
        const float invN = 1.0f / (float)((size_t)NPLANES * HH * WW);
        atomicAdd(out, -bsum * invN);
    }
}

extern "C" void kernel_launch(void* const* d_in, const int* in_sizes, int n_in,
                              void* d_out, int out_size, void* d_ws, size_t ws_size,
                              hipStream_t stream) {
    const float* img = (const float*)d_in[0];
    const float* tgt = (const float*)d_in[1];
    float* out = (float*)d_out;

    // g[i] = exp(-(i-5)^2/4.5)/s = A * 2^(-B*(i-5)^2)
    double s = 0.0;
    for (int i = 0; i < 11; ++i) {
        double d = (double)(i - 5);
        s += exp(-(d * d) / 4.5);
    }
    WParam wp;
    wp.A = (float)(1.0 / s);
    wp.B = (float)(M_LOG2E / 4.5);

    ssim_init_out<<<1, 1, 0, stream>>>(out);
    ssim_mfma<<<NBLOCKS, 256, 0, stream>>>(img, tgt, out, wp);
}

// Round 16
// 141.309 us; speedup vs baseline: 1.1612x; 1.1612x over previous
//
#include <hip/hip_runtime.h>
#include <hip/hip_fp16.h>
#include <math.h>

// SSIM loss: coalesced LDS staging + register-chained MFMA blurs (r14
// structure, validated absmax 0.0) at 8 blocks/CU residency.
// Per 64x32 tile:
//   ph1: write prefetched {x,y} regs as f16 planes {x,y} (2 planes only);
//        issue next tile's global loads (in flight across raw s_barriers).
//   compute (per wave, cols 16w..16w+15, NO LDS writes):
//     - 6 ds_read_b128: hx[mt],hy[mt] rows 16mt+cl, bytes 32w+16am
//     - s,p derived in packed f16; 12 banded K=32 H-MFMAs (Bh[j]=g[8am+j-cl-3])
//     - V-blur register-chained: H-D fragment == 16x16x16 B fragment;
//       out = Av1*B1 + Av2*B2, Av1[j]=g[4am+j-cl], Av2[j]=g[4am+j+16-cl];
//       SSIM on 8 reg pixels -> lsum.
//   2 raw barriers/tile (lgkmcnt(0)+s_barrier+sched_barrier(0)).
// Residency: LDS 20480 B x 8 blocks = 160 KiB (exact CU capacity), VGPR 56
// <= 64 cap at 8 waves/EU. G_TILES=3 -> 2048 blocks = exactly 8/CU.
// Zero-pad: rows 42-47 / cols 80-103 zero-init'd, never written; V-weights
// for staged rows 42-47 provably zero; finite*0=0 invariant (r7-r14).

#define HH 512
#define WW 512
#define HW (HH*WW)
#define NPLANES 48
#define G_TILES 3
#define NBLOCKS 2048           // 6144 tiles / 3

typedef _Float16 f16x8 __attribute__((ext_vector_type(8)));
typedef _Float16 f16x4 __attribute__((ext_vector_type(4)));
typedef float f32x4 __attribute__((ext_vector_type(4)));

#define RAW_STRIDE 208         // bytes per staged row (104 f16; 80 used)
#define RAW_PLANE  9984        // 48*208; x at 0, y at RAW_PLANE
#define LDS_TOTAL  19968       // 2 planes

struct WParam { float A, B; };

__global__ void ssim_init_out(float* out) { out[0] = 1.0f; }

__device__ __forceinline__ void barrier_nodrain() {
    asm volatile("s_waitcnt lgkmcnt(0)" ::: "memory");
    __builtin_amdgcn_s_barrier();
    __builtin_amdgcn_sched_barrier(0);
}

__global__ __launch_bounds__(256, 8)
void ssim_mfma(const float* __restrict__ img, const float* __restrict__ tgt,
               float* __restrict__ out, WParam wp) {
    __shared__ alignas(16) char lds[LDS_TOTAL];
    __shared__ float wsum[4];

    const int tid  = threadIdx.x;
    const int wid  = tid >> 6;
    const int lane = tid & 63;
    const int cl   = lane & 15;
    const int am   = lane >> 4;

    // fixed 2 staging items per thread (420 = 256 + 164)
    const int it0 = tid,       ir0 = it0 / 10, ig0 = it0 - 10 * ir0;
    const int it1 = tid + 256, ir1 = it1 / 10, ig1 = it1 - 10 * ir1;
    const bool has1 = (tid < 164);

    float4 Xa[2], Xb[2], Ya[2], Yb[2];

    auto load_tile = [&](int tlin) {
        const int p   = tlin >> 7;
        const int rem = tlin & 127;
        const int R0  = (rem >> 3) * 32;
        const int C0  = (rem & 7) * 64;
        const float* ip = img + (size_t)p * HW;
        const float* tp = tgt + (size_t)p * HW;
        #pragma unroll
        for (int s = 0; s < 2; ++s) {
            if (s == 1 && !has1) break;
            int r   = s ? ir1 : ir0;
            int grp = s ? ig1 : ig0;
            int gr  = R0 - 5 + r;
            int gc0 = C0 - 8 + grp * 8;
            float4 xa = make_float4(0.f,0.f,0.f,0.f), xb = xa, ya = xa, yb = xa;
            if ((unsigned)gr < (unsigned)HH) {
                const float* xr = ip + (size_t)gr * WW;
                const float* yr = tp + (size_t)gr * WW;
                if ((unsigned)gc0 <= (unsigned)(WW - 4)) {
                    xa = *(const float4*)(xr + gc0);
                    ya = *(const float4*)(yr + gc0);
                }
                if ((unsigned)(gc0 + 4) <= (unsigned)(WW - 4)) {
                    xb = *(const float4*)(xr + gc0 + 4);
                    yb = *(const float4*)(yr + gc0 + 4);
                }
            }
            Xa[s] = xa; Xb[s] = xb; Ya[s] = ya; Yb[s] = yb;
        }
    };

    auto write_tile = [&]() {
        #pragma unroll
        for (int s = 0; s < 2; ++s) {
            if (s == 1 && !has1) break;
            int r   = s ? ir1 : ir0;
            int grp = s ? ig1 : ig0;
            f16x8 hx, hy;
            hx[0]=(_Float16)Xa[s].x; hx[1]=(_Float16)Xa[s].y;
            hx[2]=(_Float16)Xa[s].z; hx[3]=(_Float16)Xa[s].w;
            hx[4]=(_Float16)Xb[s].x; hx[5]=(_Float16)Xb[s].y;
            hx[6]=(_Float16)Xb[s].z; hx[7]=(_Float16)Xb[s].w;
            hy[0]=(_Float16)Ya[s].x; hy[1]=(_Float16)Ya[s].y;
            hy[2]=(_Float16)Ya[s].z; hy[3]=(_Float16)Ya[s].w;
            hy[4]=(_Float16)Yb[s].x; hy[5]=(_Float16)Yb[s].y;
            hy[6]=(_Float16)Yb[s].z; hy[7]=(_Float16)Yb[s].w;
            char* base = lds + r * RAW_STRIDE + grp * 16;
            *(f16x8*)(base + 0*RAW_PLANE) = hx;
            *(f16x8*)(base + 1*RAW_PLANE) = hy;
        }
    };

    const int base_t = blockIdx.x * G_TILES;
    load_tile(base_t);                 // prologue prefetch (overlaps init)

    // ---- one-time LDS zero-init (pad rows/cols forever zero) ----
    for (int i = tid; i < LDS_TOTAL / 4; i += 256)
        ((float*)lds)[i] = 0.f;

    // ---- per-lane weight fragments ----
    f16x8 Bh;
    #pragma unroll
    for (int j = 0; j < 8; ++j) {
        int ih = 8*am + j - cl - 3;
        float t = (float)(ih - 5);
        Bh[j] = ((unsigned)ih <= 10u) ? (_Float16)(wp.A * exp2f(-wp.B*t*t))
                                      : (_Float16)0.f;
    }
    f16x4 Av1, Av2;
    #pragma unroll
    for (int j = 0; j < 4; ++j) {
        int k = 4*am + j;
        int i1 = k - cl;
        float t1 = (float)(i1 - 5);
        Av1[j] = ((unsigned)i1 <= 10u) ? (_Float16)(wp.A * exp2f(-wp.B*t1*t1))
                                       : (_Float16)0.f;
        int i2 = k + 16 - cl;
        float t2 = (float)(i2 - 5);
        Av2[j] = ((unsigned)i2 <= 10u) ? (_Float16)(wp.A * exp2f(-wp.B*t2*t2))
                                       : (_Float16)0.f;
    }
    __syncthreads();

    const float C1 = 1e-4f, C2 = 9e-4f;
    float lsum = 0.f;

    for (int g = 0; g < G_TILES; ++g) {
        // ---- phase 1: write prefetched tile to LDS; issue next prefetch ----
        write_tile();
        if (g + 1 < G_TILES) load_tile(base_t + g + 1);
        barrier_nodrain();

        // ---- compute: all-register H+V blur + SSIM (no LDS writes) ----
        {
            const int abase = cl * RAW_STRIDE + 32 * wid + am * 16;
            f16x8 hx3[3], hy3[3];
            #pragma unroll
            for (int mt = 0; mt < 3; ++mt) {
                hx3[mt] = *(const f16x8*)(lds + (16*mt) * RAW_STRIDE + abase);
                hy3[mt] = *(const f16x8*)(lds + RAW_PLANE + (16*mt) * RAW_STRIDE + abase);
            }

            f32x4 accv[4][2];
            #pragma unroll
            for (int q = 0; q < 4; ++q) {
                f32x4 Dh[3];
                #pragma unroll
                for (int mt = 0; mt < 3; ++mt) {
                    f16x8 A = (q == 0) ? hx3[mt]
                            : (q == 1) ? hy3[mt]
                            : (q == 2) ? (f16x8)(hx3[mt]*hx3[mt] + hy3[mt]*hy3[mt])
                                       : (f16x8)(hx3[mt]*hy3[mt]);
                    f32x4 zz = {0.f, 0.f, 0.f, 0.f};
                    Dh[mt] = __builtin_amdgcn_mfma_f32_16x16x32_f16(A, Bh, zz, 0, 0, 0);
                }
                #pragma unroll
                for (int mtv = 0; mtv < 2; ++mtv) {
                    f16x4 B1, B2;
                    #pragma unroll
                    for (int j = 0; j < 4; ++j) {
                        B1[j] = (_Float16)Dh[mtv][j];
                        B2[j] = (_Float16)Dh[mtv+1][j];
                    }
                    f32x4 zz = {0.f, 0.f, 0.f, 0.f};
                    f32x4 acc = __builtin_amdgcn_mfma_f32_16x16x16f16(Av2, B2, zz, 0, 0, 0);
                    accv[q][mtv] = __builtin_amdgcn_mfma_f32_16x16x16f16(Av1, B1, acc, 0, 0, 0);
                }
            }

            #pragma unroll
            for (int mtv = 0; mtv < 2; ++mtv) {
                #pragma unroll
                for (int j = 0; j < 4; ++j) {
                    float mu1 = accv[0][mtv][j], mu2 = accv[1][mtv][j];
                    float bss = accv[2][mtv][j], bxy = accv[3][mtv][j];
                    float mu1s = mu1*mu1, mu2s = mu2*mu2, mu12 = mu1*mu2;
                    float ssum = bss - mu1s - mu2s;
                    float s12  = bxy - mu12;
                    float num = (2.f*mu12 + C1) * (2.f*s12 + C2);
                    float den = (mu1s + mu2s + C1) * (ssum + C2);
                    lsum = fmaf(num, __builtin_amdgcn_rcpf(den), lsum);
                }
            }
        }
        barrier_nodrain();   // all LDS reads done before next ph1 write
    }

    // ---- block reduction + one atomic ----
    for (int off = 32; off > 0; off >>= 1)
        lsum += __shfl_down(lsum, off, 64);
    if (lane == 0) wsum[wid] = lsum;
    __syncthreads();
    if (tid == 0) {
        float bsum = wsum[0] + wsum[1] + wsum[2] + wsum[3];
        const float invN = 1.0f / (float)((size_t)NPLANES * HH * WW);
        atomicAdd(out, -bsum * invN);
    }
}

extern "C" void kernel_launch(void* const* d_in, const int* in_sizes, int n_in,
                              void* d_out, int out_size, void* d_ws, size_t ws_size,
                              hipStream_t stream) {
    const float* img = (const float*)d_in[0];
    const float* tgt = (const float*)d_in[1];
    float* out = (float*)d_out;

    // g[i] = exp(-(i-5)^2/4.5)/s = A * 2^(-B*(i-5)^2)
    double s = 0.0;
    for (int i = 0; i < 11; ++i) {
        double d = (double)(i - 5);
        s += exp(-(d * d) / 4.5);
    }
    WParam wp;
    wp.A = (float)(1.0 / s);
    wp.B = (float)(M_LOG2E / 4.5);

    ssim_init_out<<<1, 1, 0, stream>>>(out);
    ssim_mfma<<<NBLOCKS, 256, 0, stream>>>(img, tgt, out, wp);
}

// Round 17
// 133.267 us; speedup vs baseline: 1.2313x; 1.0603x over previous
//
#include <hip/hip_runtime.h>
#include <hip/hip_fp16.h>
#include <math.h>

// SSIM loss: coalesced LDS staging + register-chained MFMA blurs (r14
// structure, validated absmax 0.0) at 6 blocks/CU residency.
// Per 64x32 tile:
//   ph1: write prefetched {x,y} regs as f16 planes {x,y} (2 planes only);
//        issue next tile's global loads (in flight across raw s_barriers).
//   compute (per wave, cols 16w..16w+15, NO LDS writes):
//     - 6 ds_read_b128: hx[mt],hy[mt] rows 16mt+cl, bytes 32w+16am
//     - s,p derived in packed f16; 12 banded K=32 H-MFMAs (Bh[j]=g[8am+j-cl-3])
//     - V-blur register-chained: H-D fragment == 16x16x16 B fragment;
//       out = Av1*B1 + Av2*B2, Av1[j]=g[4am+j-cl], Av2[j]=g[4am+j+16-cl];
//       SSIM on 8 reg pixels -> lsum.
//   2 raw barriers/tile (lgkmcnt(0)+s_barrier+sched_barrier(0)).
// Residency: (256,6) -> VGPR cap ~84 >= 56 needed (NO spill; r15/r16 lesson:
// any cap below ~56 produces 100+ MB scratch traffic and 3x slowdown).
// LDS 20480 x 6 = 123 KB <= 160 KB. G_TILES=4 -> 1536 blocks = exactly 6/CU.
// Zero-pad: rows 42-47 / cols 80-103 zero-init'd, never written; V-weights
// for staged rows 42-47 provably zero; finite*0=0 invariant (r7-r14).

#define HH 512
#define WW 512
#define HW (HH*WW)
#define NPLANES 48
#define G_TILES 4
#define NBLOCKS 1536           // 6144 tiles / 4

typedef _Float16 f16x8 __attribute__((ext_vector_type(8)));
typedef _Float16 f16x4 __attribute__((ext_vector_type(4)));
typedef float f32x4 __attribute__((ext_vector_type(4)));

#define RAW_STRIDE 208         // bytes per staged row (104 f16; 80 used)
#define RAW_PLANE  9984        // 48*208; x at 0, y at RAW_PLANE
#define LDS_TOTAL  19968       // 2 planes

struct WParam { float A, B; };

__global__ void ssim_init_out(float* out) { out[0] = 1.0f; }

__device__ __forceinline__ void barrier_nodrain() {
    asm volatile("s_waitcnt lgkmcnt(0)" ::: "memory");
    __builtin_amdgcn_s_barrier();
    __builtin_amdgcn_sched_barrier(0);
}

__global__ __launch_bounds__(256, 6)
void ssim_mfma(const float* __restrict__ img, const float* __restrict__ tgt,
               float* __restrict__ out, WParam wp) {
    __shared__ alignas(16) char lds[LDS_TOTAL];
    __shared__ float wsum[4];

    const int tid  = threadIdx.x;
    const int wid  = tid >> 6;
    const int lane = tid & 63;
    const int cl   = lane & 15;
    const int am   = lane >> 4;

    // fixed 2 staging items per thread (420 = 256 + 164)
    const int it0 = tid,       ir0 = it0 / 10, ig0 = it0 - 10 * ir0;
    const int it1 = tid + 256, ir1 = it1 / 10, ig1 = it1 - 10 * ir1;
    const bool has1 = (tid < 164);

    float4 Xa[2], Xb[2], Ya[2], Yb[2];

    auto load_tile = [&](int tlin) {
        const int p   = tlin >> 7;
        const int rem = tlin & 127;
        const int R0  = (rem >> 3) * 32;
        const int C0  = (rem & 7) * 64;
        const float* ip = img + (size_t)p * HW;
        const float* tp = tgt + (size_t)p * HW;
        #pragma unroll
        for (int s = 0; s < 2; ++s) {
            if (s == 1 && !has1) break;
            int r   = s ? ir1 : ir0;
            int grp = s ? ig1 : ig0;
            int gr  = R0 - 5 + r;
            int gc0 = C0 - 8 + grp * 8;
            float4 xa = make_float4(0.f,0.f,0.f,0.f), xb = xa, ya = xa, yb = xa;
            if ((unsigned)gr < (unsigned)HH) {
                const float* xr = ip + (size_t)gr * WW;
                const float* yr = tp + (size_t)gr * WW;
                if ((unsigned)gc0 <= (unsigned)(WW - 4)) {
                    xa = *(const float4*)(xr + gc0);
                    ya = *(const float4*)(yr + gc0);
                }
                if ((unsigned)(gc0 + 4) <= (unsigned)(WW - 4)) {
                    xb = *(const float4*)(xr + gc0 + 4);
                    yb = *(const float4*)(yr + gc0 + 4);
                }
            }
            Xa[s] = xa; Xb[s] = xb; Ya[s] = ya; Yb[s] = yb;
        }
    };

    auto write_tile = [&]() {
        #pragma unroll
        for (int s = 0; s < 2; ++s) {
            if (s == 1 && !has1) break;
            int r   = s ? ir1 : ir0;
            int grp = s ? ig1 : ig0;
            f16x8 hx, hy;
            hx[0]=(_Float16)Xa[s].x; hx[1]=(_Float16)Xa[s].y;
            hx[2]=(_Float16)Xa[s].z; hx[3]=(_Float16)Xa[s].w;
            hx[4]=(_Float16)Xb[s].x; hx[5]=(_Float16)Xb[s].y;
            hx[6]=(_Float16)Xb[s].z; hx[7]=(_Float16)Xb[s].w;
            hy[0]=(_Float16)Ya[s].x; hy[1]=(_Float16)Ya[s].y;
            hy[2]=(_Float16)Ya[s].z; hy[3]=(_Float16)Ya[s].w;
            hy[4]=(_Float16)Yb[s].x; hy[5]=(_Float16)Yb[s].y;
            hy[6]=(_Float16)Yb[s].z; hy[7]=(_Float16)Yb[s].w;
            char* base = lds + r * RAW_STRIDE + grp * 16;
            *(f16x8*)(base + 0*RAW_PLANE) = hx;
            *(f16x8*)(base + 1*RAW_PLANE) = hy;
        }
    };

    const int base_t = blockIdx.x * G_TILES;
    load_tile(base_t);                 // prologue prefetch (overlaps init)

    // ---- one-time LDS zero-init (pad rows/cols forever zero) ----
    for (int i = tid; i < LDS_TOTAL / 4; i += 256)
        ((float*)lds)[i] = 0.f;

    // ---- per-lane weight fragments ----
    f16x8 Bh;
    #pragma unroll
    for (int j = 0; j < 8; ++j) {
        int ih = 8*am + j - cl - 3;
        float t = (float)(ih - 5);
        Bh[j] = ((unsigned)ih <= 10u) ? (_Float16)(wp.A * exp2f(-wp.B*t*t))
                                      : (_Float16)0.f;
    }
    f16x4 Av1, Av2;
    #pragma unroll
    for (int j = 0; j < 4; ++j) {
        int k = 4*am + j;
        int i1 = k - cl;
        float t1 = (float)(i1 - 5);
        Av1[j] = ((unsigned)i1 <= 10u) ? (_Float16)(wp.A * exp2f(-wp.B*t1*t1))
                                       : (_Float16)0.f;
        int i2 = k + 16 - cl;
        float t2 = (float)(i2 - 5);
        Av2[j] = ((unsigned)i2 <= 10u) ? (_Float16)(wp.A * exp2f(-wp.B*t2*t2))
                                       : (_Float16)0.f;
    }
    __syncthreads();

    const float C1 = 1e-4f, C2 = 9e-4f;
    float lsum = 0.f;

    for (int g = 0; g < G_TILES; ++g) {
        // ---- phase 1: write prefetched tile to LDS; issue next prefetch ----
        write_tile();
        if (g + 1 < G_TILES) load_tile(base_t + g + 1);
        barrier_nodrain();

        // ---- compute: all-register H+V blur + SSIM (no LDS writes) ----
        {
            const int abase = cl * RAW_STRIDE + 32 * wid + am * 16;
            f16x8 hx3[3], hy3[3];
            #pragma unroll
            for (int mt = 0; mt < 3; ++mt) {
                hx3[mt] = *(const f16x8*)(lds + (16*mt) * RAW_STRIDE + abase);
                hy3[mt] = *(const f16x8*)(lds + RAW_PLANE + (16*mt) * RAW_STRIDE + abase);
            }

            f32x4 accv[4][2];
            #pragma unroll
            for (int q = 0; q < 4; ++q) {
                f32x4 Dh[3];
                #pragma unroll
                for (int mt = 0; mt < 3; ++mt) {
                    f16x8 A = (q == 0) ? hx3[mt]
                            : (q == 1) ? hy3[mt]
                            : (q == 2) ? (f16x8)(hx3[mt]*hx3[mt] + hy3[mt]*hy3[mt])
                                       : (f16x8)(hx3[mt]*hy3[mt]);
                    f32x4 zz = {0.f, 0.f, 0.f, 0.f};
                    Dh[mt] = __builtin_amdgcn_mfma_f32_16x16x32_f16(A, Bh, zz, 0, 0, 0);
                }
                #pragma unroll
                for (int mtv = 0; mtv < 2; ++mtv) {
                    f16x4 B1, B2;
                    #pragma unroll
                    for (int j = 0; j < 4; ++j) {
                        B1[j] = (_Float16)Dh[mtv][j];
                        B2[j] = (_Float16)Dh[mtv+1][j];
                    }
                    f32x4 zz = {0.f, 0.f, 0.f, 0.f};
                    f32x4 acc = __builtin_amdgcn_mfma_f32_16x16x16f16(Av2, B2, zz, 0, 0, 0);
                    accv[q][mtv] = __builtin_amdgcn_mfma_f32_16x16x16f16(Av1, B1, acc, 0, 0, 0);
                }
            }

            #pragma unroll
            for (int mtv = 0; mtv < 2; ++mtv) {
                #pragma unroll
                for (int j = 0; j < 4; ++j) {
                    float mu1 = accv[0][mtv][j], mu2 = accv[1][mtv][j];
                    float bss = accv[2][mtv][j], bxy = accv[3][mtv][j];
                    float mu1s = mu1*mu1, mu2s = mu2*mu2, mu12 = mu1*mu2;
                    float ssum = bss - mu1s - mu2s;
                    float s12  = bxy - mu12;
                    float num = (2.f*mu12 + C1) * (2.f*s12 + C2);
                    float den = (mu1s + mu2s + C1) * (ssum + C2);
                    lsum = fmaf(num, __builtin_amdgcn_rcpf(den), lsum);
                }
            }
        }
        barrier_nodrain();   // all LDS reads done before next ph1 write
    }

    // ---- block reduction + one atomic ----
    for (int off = 32; off > 0; off >>= 1)
        lsum += __shfl_down(lsum, off, 64);
    if (lane == 0) wsum[wid] = lsum;
    __syncthreads();
    if (tid == 0) {
        float bsum = wsum[0] + wsum[1] + wsum[2] + wsum[3];
        const float invN = 1.0f / (float)((size_t)NPLANES * HH * WW);
        atomicAdd(out, -bsum * invN);
    }
}

extern "C" void kernel_launch(void* const* d_in, const int* in_sizes, int n_in,
                              void* d_out, int out_size, void* d_ws, size_t ws_size,
                              hipStream_t stream) {
    const float* img = (const float*)d_in[0];
    const float* tgt = (const float*)d_in[1];
    float* out = (float*)d_out;

    // g[i] = exp(-(i-5)^2/4.5)/s = A * 2^(-B*(i-5)^2)
    double s = 0.0;
    for (int i = 0; i < 11; ++i) {
        double d = (double)(i - 5);
        s += exp(-(d * d) / 4.5);
    }
    WParam wp;
    wp.A = (float)(1.0 / s);
    wp.B = (float)(M_LOG2E / 4.5);

    ssim_init_out<<<1, 1, 0, stream>>>(out);
    ssim_mfma<<<NBLOCKS, 256, 0, stream>>>(img, tgt, out, wp);
}

// Round 18
// 52.752 us; speedup vs baseline: 3.1106x; 2.5263x over previous
//
#include <hip/hip_runtime.h>
#include <hip/hip_fp16.h>
#include <math.h>

// SSIM loss: coalesced LDS staging + register-chained MFMA blurs (r14
// structure, validated absmax 0.0), grid raised to 8 assigned blocks/CU.
// Per 64x32 tile:
//   ph1: write prefetched {x,y} regs as f16 planes {x,y} (2 planes only);
//        issue next tile's global loads (in flight across raw s_barriers).
//   compute (per wave, cols 16w..16w+15, NO LDS writes):
//     - 6 ds_read_b128: hx[mt],hy[mt] rows 16mt+cl, bytes 32w+16am
//     - s,p derived in packed f16; 12 banded K=32 H-MFMAs (Bh[j]=g[8am+j-cl-3])
//     - V-blur register-chained: H-D fragment == 16x16x16 B fragment;
//       out = Av1*B1 + Av2*B2, Av1[j]=g[4am+j-cl], Av2[j]=g[4am+j+16-cl];
//       SSIM on 8 reg pixels -> lsum.
//   2 raw barriers/tile (lgkmcnt(0)+s_barrier+sched_barrier(0)).
// LAUNCH BOUNDS MUST STAY (256,4): gfx950 unified VGPR/AGPR file splits the
// per-wave budget; (256,8)->32 arch, (256,6)->40 arch, both below this
// kernel's ~56 arch need -> 100-300 MB scratch and 3x slowdown (r15-r17).
// Residency comes from the GRID instead: G_TILES=3 -> 2048 blocks = 8/CU
// assigned; LDS fits 8 (8x20480=160KiB), VGPR pool fits ~6 -> ~6 resident.
// Zero-pad: rows 42-47 / cols 80-103 zero-init'd, never written; V-weights
// for staged rows 42-47 provably zero; finite*0=0 invariant (r7-r14).

#define HH 512
#define WW 512
#define HW (HH*WW)
#define NPLANES 48
#define G_TILES 3
#define NBLOCKS 2048           // 6144 tiles / 3

typedef _Float16 f16x8 __attribute__((ext_vector_type(8)));
typedef _Float16 f16x4 __attribute__((ext_vector_type(4)));
typedef float f32x4 __attribute__((ext_vector_type(4)));

#define RAW_STRIDE 208         // bytes per staged row (104 f16; 80 used)
#define RAW_PLANE  9984        // 48*208; x at 0, y at RAW_PLANE
#define LDS_TOTAL  19968       // 2 planes

struct WParam { float A, B; };

__global__ void ssim_init_out(float* out) { out[0] = 1.0f; }

__device__ __forceinline__ void barrier_nodrain() {
    asm volatile("s_waitcnt lgkmcnt(0)" ::: "memory");
    __builtin_amdgcn_s_barrier();
    __builtin_amdgcn_sched_barrier(0);
}

__global__ __launch_bounds__(256, 4)
void ssim_mfma(const float* __restrict__ img, const float* __restrict__ tgt,
               float* __restrict__ out, WParam wp) {
    __shared__ alignas(16) char lds[LDS_TOTAL];
    __shared__ float wsum[4];

    const int tid  = threadIdx.x;
    const int wid  = tid >> 6;
    const int lane = tid & 63;
    const int cl   = lane & 15;
    const int am   = lane >> 4;

    // fixed 2 staging items per thread (420 = 256 + 164)
    const int it0 = tid,       ir0 = it0 / 10, ig0 = it0 - 10 * ir0;
    const int it1 = tid + 256, ir1 = it1 / 10, ig1 = it1 - 10 * ir1;
    const bool has1 = (tid < 164);

    float4 Xa[2], Xb[2], Ya[2], Yb[2];

    auto load_tile = [&](int tlin) {
        const int p   = tlin >> 7;
        const int rem = tlin & 127;
        const int R0  = (rem >> 3) * 32;
        const int C0  = (rem & 7) * 64;
        const float* ip = img + (size_t)p * HW;
        const float* tp = tgt + (size_t)p * HW;
        #pragma unroll
        for (int s = 0; s < 2; ++s) {
            if (s == 1 && !has1) break;
            int r   = s ? ir1 : ir0;
            int grp = s ? ig1 : ig0;
            int gr  = R0 - 5 + r;
            int gc0 = C0 - 8 + grp * 8;
            float4 xa = make_float4(0.f,0.f,0.f,0.f), xb = xa, ya = xa, yb = xa;
            if ((unsigned)gr < (unsigned)HH) {
                const float* xr = ip + (size_t)gr * WW;
                const float* yr = tp + (size_t)gr * WW;
                if ((unsigned)gc0 <= (unsigned)(WW - 4)) {
                    xa = *(const float4*)(xr + gc0);
                    ya = *(const float4*)(yr + gc0);
                }
                if ((unsigned)(gc0 + 4) <= (unsigned)(WW - 4)) {
                    xb = *(const float4*)(xr + gc0 + 4);
                    yb = *(const float4*)(yr + gc0 + 4);
                }
            }
            Xa[s] = xa; Xb[s] = xb; Ya[s] = ya; Yb[s] = yb;
        }
    };

    auto write_tile = [&]() {
        #pragma unroll
        for (int s = 0; s < 2; ++s) {
            if (s == 1 && !has1) break;
            int r   = s ? ir1 : ir0;
            int grp = s ? ig1 : ig0;
            f16x8 hx, hy;
            hx[0]=(_Float16)Xa[s].x; hx[1]=(_Float16)Xa[s].y;
            hx[2]=(_Float16)Xa[s].z; hx[3]=(_Float16)Xa[s].w;
            hx[4]=(_Float16)Xb[s].x; hx[5]=(_Float16)Xb[s].y;
            hx[6]=(_Float16)Xb[s].z; hx[7]=(_Float16)Xb[s].w;
            hy[0]=(_Float16)Ya[s].x; hy[1]=(_Float16)Ya[s].y;
            hy[2]=(_Float16)Ya[s].z; hy[3]=(_Float16)Ya[s].w;
            hy[4]=(_Float16)Yb[s].x; hy[5]=(_Float16)Yb[s].y;
            hy[6]=(_Float16)Yb[s].z; hy[7]=(_Float16)Yb[s].w;
            char* base = lds + r * RAW_STRIDE + grp * 16;
            *(f16x8*)(base + 0*RAW_PLANE) = hx;
            *(f16x8*)(base + 1*RAW_PLANE) = hy;
        }
    };

    const int base_t = blockIdx.x * G_TILES;
    load_tile(base_t);                 // prologue prefetch (overlaps init)

    // ---- one-time LDS zero-init (pad rows/cols forever zero) ----
    for (int i = tid; i < LDS_TOTAL / 4; i += 256)
        ((float*)lds)[i] = 0.f;

    // ---- per-lane weight fragments ----
    f16x8 Bh;
    #pragma unroll
    for (int j = 0; j < 8; ++j) {
        int ih = 8*am + j - cl - 3;
        float t = (float)(ih - 5);
        Bh[j] = ((unsigned)ih <= 10u) ? (_Float16)(wp.A * exp2f(-wp.B*t*t))
                                      : (_Float16)0.f;
    }
    f16x4 Av1, Av2;
    #pragma unroll
    for (int j = 0; j < 4; ++j) {
        int k = 4*am + j;
        int i1 = k - cl;
        float t1 = (float)(i1 - 5);
        Av1[j] = ((unsigned)i1 <= 10u) ? (_Float16)(wp.A * exp2f(-wp.B*t1*t1))
                                       : (_Float16)0.f;
        int i2 = k + 16 - cl;
        float t2 = (float)(i2 - 5);
        Av2[j] = ((unsigned)i2 <= 10u) ? (_Float16)(wp.A * exp2f(-wp.B*t2*t2))
                                       : (_Float16)0.f;
    }
    __syncthreads();

    const float C1 = 1e-4f, C2 = 9e-4f;
    float lsum = 0.f;

    for (int g = 0; g < G_TILES; ++g) {
        // ---- phase 1: write prefetched tile to LDS; issue next prefetch ----
        write_tile();
        if (g + 1 < G_TILES) load_tile(base_t + g + 1);
        barrier_nodrain();

        // ---- compute: all-register H+V blur + SSIM (no LDS writes) ----
        {
            const int abase = cl * RAW_STRIDE + 32 * wid + am * 16;
            f16x8 hx3[3], hy3[3];
            #pragma unroll
            for (int mt = 0; mt < 3; ++mt) {
                hx3[mt] = *(const f16x8*)(lds + (16*mt) * RAW_STRIDE + abase);
                hy3[mt] = *(const f16x8*)(lds + RAW_PLANE + (16*mt) * RAW_STRIDE + abase);
            }

            f32x4 accv[4][2];
            #pragma unroll
            for (int q = 0; q < 4; ++q) {
                f32x4 Dh[3];
                #pragma unroll
                for (int mt = 0; mt < 3; ++mt) {
                    f16x8 A = (q == 0) ? hx3[mt]
                            : (q == 1) ? hy3[mt]
                            : (q == 2) ? (f16x8)(hx3[mt]*hx3[mt] + hy3[mt]*hy3[mt])
                                       : (f16x8)(hx3[mt]*hy3[mt]);
                    f32x4 zz = {0.f, 0.f, 0.f, 0.f};
                    Dh[mt] = __builtin_amdgcn_mfma_f32_16x16x32_f16(A, Bh, zz, 0, 0, 0);
                }
                #pragma unroll
                for (int mtv = 0; mtv < 2; ++mtv) {
                    f16x4 B1, B2;
                    #pragma unroll
                    for (int j = 0; j < 4; ++j) {
                        B1[j] = (_Float16)Dh[mtv][j];
                        B2[j] = (_Float16)Dh[mtv+1][j];
                    }
                    f32x4 zz = {0.f, 0.f, 0.f, 0.f};
                    f32x4 acc = __builtin_amdgcn_mfma_f32_16x16x16f16(Av2, B2, zz, 0, 0, 0);
                    accv[q][mtv] = __builtin_amdgcn_mfma_f32_16x16x16f16(Av1, B1, acc, 0, 0, 0);
                }
            }

            #pragma unroll
            for (int mtv = 0; mtv < 2; ++mtv) {
                #pragma unroll
                for (int j = 0; j < 4; ++j) {
                    float mu1 = accv[0][mtv][j], mu2 = accv[1][mtv][j];
                    float bss = accv[2][mtv][j], bxy = accv[3][mtv][j];
                    float mu1s = mu1*mu1, mu2s = mu2*mu2, mu12 = mu1*mu2;
                    float ssum = bss - mu1s - mu2s;
                    float s12  = bxy - mu12;
                    float num = (2.f*mu12 + C1) * (2.f*s12 + C2);
                    float den = (mu1s + mu2s + C1) * (ssum + C2);
                    lsum = fmaf(num, __builtin_amdgcn_rcpf(den), lsum);
                }
            }
        }
        barrier_nodrain();   // all LDS reads done before next ph1 write
    }

    // ---- block reduction + one atomic ----
    for (int off = 32; off > 0; off >>= 1)
        lsum += __shfl_down(lsum, off, 64);
    if (lane == 0) wsum[wid] = lsum;
    __syncthreads();
    if (tid == 0) {
        float bsum = wsum[0] + wsum[1] + wsum[2] + wsum[3];
        const float invN = 1.0f / (float)((size_t)NPLANES * HH * WW);
        atomicAdd(out, -bsum * invN);
    }
}

extern "C" void kernel_launch(void* const* d_in, const int* in_sizes, int n_in,
                              void* d_out, int out_size, void* d_ws, size_t ws_size,
                              hipStream_t stream) {
    const float* img = (const float*)d_in[0];
    const float* tgt = (const float*)d_in[1];
    float* out = (float*)d_out;

    // g[i] = exp(-(i-5)^2/4.5)/s = A * 2^(-B*(i-5)^2)
    double s = 0.0;
    for (int i = 0; i < 11; ++i) {
        double d = (double)(i - 5);
        s += exp(-(d * d) / 4.5);
    }
    WParam wp;
    wp.A = (float)(1.0 / s);
    wp.B = (float)(M_LOG2E / 4.5);

    ssim_init_out<<<1, 1, 0, stream>>>(out);
    ssim_mfma<<<NBLOCKS, 256, 0, stream>>>(img, tgt, out, wp);
}

// Round 19
// 40.219 us; speedup vs baseline: 4.0800x; 1.3116x over previous
//
#include <hip/hip_runtime.h>
#include <hip/hip_fp16.h>
#include <math.h>

// SSIM loss: coalesced LDS staging + register-chained MFMA blurs (r14
// structure, validated absmax 0.0) + DOUBLE-BUFFERED LDS -> 1 barrier/tile.
// Per 64x32 tile:
//   ph1: write prefetched {x,y} regs as f16 planes into buf[g&1];
//        issue next tile's global loads (in flight across raw s_barrier).
//   ONE barrier (lgkmcnt(0)+s_barrier+sched_barrier(0)).
//   compute (per wave, cols 16w..16w+15, reads buf[g&1], NO LDS writes):
//     6 ds_read_b128 -> s,p in packed f16 -> 12 banded K=32 H-MFMAs
//     (Bh[j]=g[8am+j-cl-3]) -> V-blur register-chained 16x16x16
//     (Av1[j]=g[4am+j-cl], Av2[j]=g[4am+j+16-cl]) -> SSIM on 8 reg px.
//   Next iteration writes the OTHER buffer: reads of buf[q] (iter g-2)
//   complete at lgkmcnt(0) before barrier(g-1) < writes of buf[q] (iter g).
// LAUNCH BOUNDS MUST STAY (256,4): gfx950 unified VGPR/AGPR budget splits
// under higher wave bounds ((256,8)->32, (256,6)->40 arch regs) -> 100-300MB
// scratch spill, 3x slowdown (r15-r17, 3x confirmed).
// Grid: G_TILES=6 -> 1024 blocks = 4/CU assigned (r18 showed 8/CU regresses:
// FETCH +11MB halo-reuse loss). LDS 2x19968=39936B; 4 blocks = 159.7KB <=
// 160KB CU capacity. Zero-pad rows 42-47 / cols 80-103 zero-init'd (both
// buffers), never written; finite*0=0 invariant (r7-r14).

#define HH 512
#define WW 512
#define HW (HH*WW)
#define NPLANES 48
#define G_TILES 6
#define NBLOCKS 1024           // 6144 tiles / 6

typedef _Float16 f16x8 __attribute__((ext_vector_type(8)));
typedef _Float16 f16x4 __attribute__((ext_vector_type(4)));
typedef float f32x4 __attribute__((ext_vector_type(4)));

#define RAW_STRIDE 208         // bytes per staged row (104 f16; 80 used)
#define RAW_PLANE  9984        // 48*208; x at 0, y at RAW_PLANE
#define BUF_B      19968       // one buffer: 2 planes
#define LDS_TOTAL  39936       // 2 buffers (ping-pong)

struct WParam { float A, B; };

__global__ void ssim_init_out(float* out) { out[0] = 1.0f; }

__device__ __forceinline__ void barrier_nodrain() {
    asm volatile("s_waitcnt lgkmcnt(0)" ::: "memory");
    __builtin_amdgcn_s_barrier();
    __builtin_amdgcn_sched_barrier(0);
}

__global__ __launch_bounds__(256, 4)
void ssim_mfma(const float* __restrict__ img, const float* __restrict__ tgt,
               float* __restrict__ out, WParam wp) {
    __shared__ alignas(16) char lds[LDS_TOTAL];
    __shared__ float wsum[4];

    const int tid  = threadIdx.x;
    const int wid  = tid >> 6;
    const int lane = tid & 63;
    const int cl   = lane & 15;
    const int am   = lane >> 4;

    // fixed 2 staging items per thread (420 = 256 + 164)
    const int it0 = tid,       ir0 = it0 / 10, ig0 = it0 - 10 * ir0;
    const int it1 = tid + 256, ir1 = it1 / 10, ig1 = it1 - 10 * ir1;
    const bool has1 = (tid < 164);

    float4 Xa[2], Xb[2], Ya[2], Yb[2];

    auto load_tile = [&](int tlin) {
        const int p   = tlin >> 7;
        const int rem = tlin & 127;
        const int R0  = (rem >> 3) * 32;
        const int C0  = (rem & 7) * 64;
        const float* ip = img + (size_t)p * HW;
        const float* tp = tgt + (size_t)p * HW;
        #pragma unroll
        for (int s = 0; s < 2; ++s) {
            if (s == 1 && !has1) break;
            int r   = s ? ir1 : ir0;
            int grp = s ? ig1 : ig0;
            int gr  = R0 - 5 + r;
            int gc0 = C0 - 8 + grp * 8;
            float4 xa = make_float4(0.f,0.f,0.f,0.f), xb = xa, ya = xa, yb = xa;
            if ((unsigned)gr < (unsigned)HH) {
                const float* xr = ip + (size_t)gr * WW;
                const float* yr = tp + (size_t)gr * WW;
                if ((unsigned)gc0 <= (unsigned)(WW - 4)) {
                    xa = *(const float4*)(xr + gc0);
                    ya = *(const float4*)(yr + gc0);
                }
                if ((unsigned)(gc0 + 4) <= (unsigned)(WW - 4)) {
                    xb = *(const float4*)(xr + gc0 + 4);
                    yb = *(const float4*)(yr + gc0 + 4);
                }
            }
            Xa[s] = xa; Xb[s] = xb; Ya[s] = ya; Yb[s] = yb;
        }
    };

    auto write_tile = [&](char* buf) {
        #pragma unroll
        for (int s = 0; s < 2; ++s) {
            if (s == 1 && !has1) break;
            int r   = s ? ir1 : ir0;
            int grp = s ? ig1 : ig0;
            f16x8 hx, hy;
            hx[0]=(_Float16)Xa[s].x; hx[1]=(_Float16)Xa[s].y;
            hx[2]=(_Float16)Xa[s].z; hx[3]=(_Float16)Xa[s].w;
            hx[4]=(_Float16)Xb[s].x; hx[5]=(_Float16)Xb[s].y;
            hx[6]=(_Float16)Xb[s].z; hx[7]=(_Float16)Xb[s].w;
            hy[0]=(_Float16)Ya[s].x; hy[1]=(_Float16)Ya[s].y;
            hy[2]=(_Float16)Ya[s].z; hy[3]=(_Float16)Ya[s].w;
            hy[4]=(_Float16)Yb[s].x; hy[5]=(_Float16)Yb[s].y;
            hy[6]=(_Float16)Yb[s].z; hy[7]=(_Float16)Yb[s].w;
            char* base = buf + r * RAW_STRIDE + grp * 16;
            *(f16x8*)(base + 0*RAW_PLANE) = hx;
            *(f16x8*)(base + 1*RAW_PLANE) = hy;
        }
    };

    const int base_t = blockIdx.x * G_TILES;
    load_tile(base_t);                 // prologue prefetch (overlaps init)

    // ---- one-time LDS zero-init, BOTH buffers (pad regions stay zero) ----
    for (int i = tid; i < LDS_TOTAL / 4; i += 256)
        ((float*)lds)[i] = 0.f;

    // ---- per-lane weight fragments ----
    f16x8 Bh;
    #pragma unroll
    for (int j = 0; j < 8; ++j) {
        int ih = 8*am + j - cl - 3;
        float t = (float)(ih - 5);
        Bh[j] = ((unsigned)ih <= 10u) ? (_Float16)(wp.A * exp2f(-wp.B*t*t))
                                      : (_Float16)0.f;
    }
    f16x4 Av1, Av2;
    #pragma unroll
    for (int j = 0; j < 4; ++j) {
        int k = 4*am + j;
        int i1 = k - cl;
        float t1 = (float)(i1 - 5);
        Av1[j] = ((unsigned)i1 <= 10u) ? (_Float16)(wp.A * exp2f(-wp.B*t1*t1))
                                       : (_Float16)0.f;
        int i2 = k + 16 - cl;
        float t2 = (float)(i2 - 5);
        Av2[j] = ((unsigned)i2 <= 10u) ? (_Float16)(wp.A * exp2f(-wp.B*t2*t2))
                                       : (_Float16)0.f;
    }
    __syncthreads();

    const float C1 = 1e-4f, C2 = 9e-4f;
    float lsum = 0.f;

    for (int g = 0; g < G_TILES; ++g) {
        char* buf = lds + (g & 1) * BUF_B;

        // ---- phase 1: write prefetched tile to buf; issue next prefetch ----
        write_tile(buf);
        if (g + 1 < G_TILES) load_tile(base_t + g + 1);
        barrier_nodrain();             // the ONLY barrier in the loop

        // ---- compute: all-register H+V blur + SSIM (no LDS writes) ----
        {
            const int abase = cl * RAW_STRIDE + 32 * wid + am * 16;
            f16x8 hx3[3], hy3[3];
            #pragma unroll
            for (int mt = 0; mt < 3; ++mt) {
                hx3[mt] = *(const f16x8*)(buf + (16*mt) * RAW_STRIDE + abase);
                hy3[mt] = *(const f16x8*)(buf + RAW_PLANE + (16*mt) * RAW_STRIDE + abase);
            }

            f32x4 accv[4][2];
            #pragma unroll
            for (int q = 0; q < 4; ++q) {
                f32x4 Dh[3];
                #pragma unroll
                for (int mt = 0; mt < 3; ++mt) {
                    f16x8 A = (q == 0) ? hx3[mt]
                            : (q == 1) ? hy3[mt]
                            : (q == 2) ? (f16x8)(hx3[mt]*hx3[mt] + hy3[mt]*hy3[mt])
                                       : (f16x8)(hx3[mt]*hy3[mt]);
                    f32x4 zz = {0.f, 0.f, 0.f, 0.f};
                    Dh[mt] = __builtin_amdgcn_mfma_f32_16x16x32_f16(A, Bh, zz, 0, 0, 0);
                }
                #pragma unroll
                for (int mtv = 0; mtv < 2; ++mtv) {
                    f16x4 B1, B2;
                    #pragma unroll
                    for (int j = 0; j < 4; ++j) {
                        B1[j] = (_Float16)Dh[mtv][j];
                        B2[j] = (_Float16)Dh[mtv+1][j];
                    }
                    f32x4 zz = {0.f, 0.f, 0.f, 0.f};
                    f32x4 acc = __builtin_amdgcn_mfma_f32_16x16x16f16(Av2, B2, zz, 0, 0, 0);
                    accv[q][mtv] = __builtin_amdgcn_mfma_f32_16x16x16f16(Av1, B1, acc, 0, 0, 0);
                }
            }

            #pragma unroll
            for (int mtv = 0; mtv < 2; ++mtv) {
                #pragma unroll
                for (int j = 0; j < 4; ++j) {
                    float mu1 = accv[0][mtv][j], mu2 = accv[1][mtv][j];
                    float bss = accv[2][mtv][j], bxy = accv[3][mtv][j];
                    float mu1s = mu1*mu1, mu2s = mu2*mu2, mu12 = mu1*mu2;
                    float ssum = bss - mu1s - mu2s;
                    float s12  = bxy - mu12;
                    float num = (2.f*mu12 + C1) * (2.f*s12 + C2);
                    float den = (mu1s + mu2s + C1) * (ssum + C2);
                    lsum = fmaf(num, __builtin_amdgcn_rcpf(den), lsum);
                }
            }
        }
        // no trailing barrier: next iteration writes the OTHER buffer
    }

    // ---- block reduction + one atomic ----
    for (int off = 32; off > 0; off >>= 1)
        lsum += __shfl_down(lsum, off, 64);
    if (lane == 0) wsum[wid] = lsum;
    __syncthreads();
    if (tid == 0) {
        float bsum = wsum[0] + wsum[1] + wsum[2] + wsum[3];
        const float invN = 1.0f / (float)((size_t)NPLANES * HH * WW);
        atomicAdd(out, -bsum * invN);
    }
}

extern "C" void kernel_launch(void* const* d_in, const int* in_sizes, int n_in,
                              void* d_out, int out_size, void* d_ws, size_t ws_size,
                              hipStream_t stream) {
    const float* img = (const float*)d_in[0];
    const float* tgt = (const float*)d_in[1];
    float* out = (float*)d_out;

    // g[i] = exp(-(i-5)^2/4.5)/s = A * 2^(-B*(i-5)^2)
    double s = 0.0;
    for (int i = 0; i < 11; ++i) {
        double d = (double)(i - 5);
        s += exp(-(d * d) / 4.5);
    }
    WParam wp;
    wp.A = (float)(1.0 / s);
    wp.B = (float)(M_LOG2E / 4.5);

    ssim_init_out<<<1, 1, 0, stream>>>(out);
    ssim_mfma<<<NBLOCKS, 256, 0, stream>>>(img, tgt, out, wp);
}